// Round 1
// baseline (931.902 us; speedup 1.0000x reference)
//
#include <hip/hip_runtime.h>
#include <hip/hip_bf16.h>

#define T_LEN 2048
#define HID_DIM 2048
#define NH 16
#define NKV 2
#define HD 256
#define ROT 64
#define EPS_F 1e-6f
#define SCALE_F 0.0625f   // 256^-0.5
#define THETA_F 10000000.0f

typedef __bf16 bf16x8 __attribute__((ext_vector_type(8)));
typedef float floatx4 __attribute__((ext_vector_type(4)));

__device__ __forceinline__ unsigned short f2bf(float x) {
  unsigned int u = __float_as_uint(x);
  unsigned int rounding = 0x7FFFu + ((u >> 16) & 1u);
  return (unsigned short)((u + rounding) >> 16);
}
__device__ __forceinline__ float bf2f(unsigned short u) {
  return __uint_as_float(((unsigned int)u) << 16);
}

__device__ __forceinline__ floatx4 mfma16(bf16x8 a, bf16x8 b, floatx4 c) {
  return __builtin_amdgcn_mfma_f32_16x16x32_bf16(a, b, c, 0, 0, 0);
}

// ---------------- fp32 -> bf16 conversion (vectorized x4) ----------------
__global__ __launch_bounds__(256) void cvt_f32_bf16(
    const float* __restrict__ in, unsigned short* __restrict__ out, int n4) {
  int i = blockIdx.x * 256 + threadIdx.x;
  if (i >= n4) return;
  float4 v = reinterpret_cast<const float4*>(in)[i];
  ushort4 o;
  o.x = f2bf(v.x); o.y = f2bf(v.y); o.z = f2bf(v.z); o.w = f2bf(v.w);
  reinterpret_cast<ushort4*>(out)[i] = o;
}

// ---------------- bf16 GEMM: C[M,N] = A[M,K] * B[N,K]^T ----------------
// A,B row-major K-contiguous bf16 bits. C fp32 or bf16 per flag.
// 128x128 tile, BK=32, 4 waves (2x2), each wave 64x64 = 4x4 MFMA 16x16x32.
__global__ __launch_bounds__(256) void gemm_bf16_bt(
    const unsigned short* __restrict__ A,
    const unsigned short* __restrict__ B,
    void* __restrict__ Cv, int M, int N, int K, int c_bf16) {
  __shared__ alignas(16) unsigned short As[128 * 32];
  __shared__ alignas(16) unsigned short Bs[128 * 32];
  const int tid = threadIdx.x;
  const int m0 = blockIdx.y * 128;
  const int n0 = blockIdx.x * 128;
  const int lane = tid & 63;
  const int wave = tid >> 6;
  const int wm = (wave >> 1) * 64;
  const int wn = (wave & 1) * 64;
  const int lrow = lane & 15;
  const int kgrp = lane >> 4;
  const int srow = tid >> 2;        // 0..63
  const int scol = (tid & 3) * 8;   // 0,8,16,24

  floatx4 acc[4][4];
#pragma unroll
  for (int i = 0; i < 4; i++)
#pragma unroll
    for (int j = 0; j < 4; j++) acc[i][j] = floatx4{0.f, 0.f, 0.f, 0.f};

  for (int k0 = 0; k0 < K; k0 += 32) {
#pragma unroll
    for (int half = 0; half < 2; ++half) {
      int r = srow + half * 64;
      *reinterpret_cast<float4*>(&As[r * 32 + scol]) =
          *reinterpret_cast<const float4*>(&A[(size_t)(m0 + r) * K + k0 + scol]);
      *reinterpret_cast<float4*>(&Bs[r * 32 + scol]) =
          *reinterpret_cast<const float4*>(&B[(size_t)(n0 + r) * K + k0 + scol]);
    }
    __syncthreads();
    bf16x8 af[4], bfr[4];
#pragma unroll
    for (int i = 0; i < 4; i++)
      af[i] = *reinterpret_cast<const bf16x8*>(&As[(wm + i * 16 + lrow) * 32 + kgrp * 8]);
#pragma unroll
    for (int j = 0; j < 4; j++)
      bfr[j] = *reinterpret_cast<const bf16x8*>(&Bs[(wn + j * 16 + lrow) * 32 + kgrp * 8]);
#pragma unroll
    for (int i = 0; i < 4; i++)
#pragma unroll
      for (int j = 0; j < 4; j++)
        acc[i][j] = mfma16(af[i], bfr[j], acc[i][j]);
    __syncthreads();
  }

  // C/D layout: col = lane&15, row = (lane>>4)*4 + reg  [m89/m91 verified]
  if (c_bf16) {
    unsigned short* C = (unsigned short*)Cv;
#pragma unroll
    for (int i = 0; i < 4; i++) {
      int row = m0 + wm + i * 16 + kgrp * 4;
#pragma unroll
      for (int j = 0; j < 4; j++) {
        int col = n0 + wn + j * 16 + lrow;
#pragma unroll
        for (int r = 0; r < 4; r++)
          C[(size_t)(row + r) * N + col] = f2bf(acc[i][j][r]);
      }
    }
  } else {
    float* C = (float*)Cv;
#pragma unroll
    for (int i = 0; i < 4; i++) {
      int row = m0 + wm + i * 16 + kgrp * 4;
#pragma unroll
      for (int j = 0; j < 4; j++) {
        int col = n0 + wn + j * 16 + lrow;
#pragma unroll
        for (int r = 0; r < 4; r++)
          C[(size_t)(row + r) * N + col] = acc[i][j][r];
      }
    }
  }
}

// ---------------- RMSNorm + partial RoPE (per (t, head), D=256) ----------------
// in: bf16 (T, in_rs) rows; head slice at h*in_hs. out: bf16 at t*out_rs + h*256.
__global__ __launch_bounds__(256) void norm_rope(
    const unsigned short* __restrict__ in, const float* __restrict__ w,
    const int* __restrict__ pos, unsigned short* __restrict__ outb,
    int in_rs, int in_hs, int out_rs) {
  const int t = blockIdx.x, h = blockIdx.y, d = threadIdx.x;
  float x = bf2f(in[(size_t)t * in_rs + h * in_hs + d]);
  float ss = x * x;
#pragma unroll
  for (int m = 32; m >= 1; m >>= 1) ss += __shfl_xor(ss, m);
  __shared__ float wsum[4];
  if ((d & 63) == 0) wsum[d >> 6] = ss;
  __syncthreads();
  float tot = (wsum[0] + wsum[1]) + (wsum[2] + wsum[3]);
  float rms = rsqrtf(tot * (1.0f / 256.0f) + EPS_F);
  float y = x * rms * (1.0f + w[d]);
  float o = y;
  if (d < ROT) {  // wave-uniform branch: d<64 is exactly wave 0
    float partner = __shfl_xor(y, ROT / 2);
    int i = d & (ROT / 2 - 1);
    float fr = (float)pos[t] * powf(THETA_F, -(float)i / (float)(ROT / 2));
    float c = cosf(fr), s = sinf(fr);
    o = (d < ROT / 2) ? (y * c - partner * s) : (partner * s + y * c);
  }
  outb[(size_t)t * out_rs + h * HD + d] = f2bf(o);
}

// ---------------- V transpose: (T, KV*D) -> (KV*D, T), bf16 ----------------
__global__ __launch_bounds__(256) void vtrans(
    const unsigned short* __restrict__ vin, unsigned short* __restrict__ vT) {
  int gid = blockIdx.x * 256 + threadIdx.x;  // gid = c*T + t
  int t = gid & (T_LEN - 1);
  int c = gid >> 11;
  vT[gid] = vin[(size_t)t * (NKV * HD) + c];
}

// ---------------- Flash attention + sigmoid gate ----------------
// Grid (T/64, H), block 256 (4 waves). Wave w handles q rows [bq*64+w*16, +16).
__global__ __launch_bounds__(256) void attn_fwd(
    const unsigned short* __restrict__ qbf,   // (T, H*D) post norm+rope
    const unsigned short* __restrict__ kbf,   // (T, KV*D) post norm+rope
    const unsigned short* __restrict__ vT,    // (KV*D, T)
    const unsigned short* __restrict__ qout,  // (T, H*2D) bf16, gate at +D
    unsigned short* __restrict__ og)          // (T, H*D) gated output
{
  const int bq = blockIdx.x;
  const int h = blockIdx.y;
  const int wave = threadIdx.x >> 6;
  const int lane = threadIdx.x & 63;
  const int lrow = lane & 15;
  const int kgrp = lane >> 4;
  const int q0 = bq * 64 + wave * 16;
  const int kv = h >> 3;  // H/KV = 8, jnp.repeat -> head h uses kv h/8

  __shared__ alignas(16) unsigned short Pl[4][16 * 32];  // per-wave P transpose buf

  // Q A-fragments: A[m=lane&15][k=(lane>>4)*8+j], 8 k-steps over D=256
  bf16x8 qa[8];
  {
    const unsigned short* qrow = qbf + (size_t)(q0 + lrow) * (NH * HD) + h * HD;
#pragma unroll
    for (int s = 0; s < 8; s++)
      qa[s] = *reinterpret_cast<const bf16x8*>(&qrow[s * 32 + kgrp * 8]);
  }

  float m_i[4], l_i[4];
#pragma unroll
  for (int r = 0; r < 4; r++) { m_i[r] = -INFINITY; l_i[r] = 0.0f; }
  floatx4 oacc[16];
#pragma unroll
  for (int dt = 0; dt < 16; dt++) oacc[dt] = floatx4{0.f, 0.f, 0.f, 0.f};

  const int qmax = q0 + 15;
  for (int kb = 0; kb <= qmax; kb += 32) {
    // S = Q K^T for 32 keys, two 16-col tiles. B-frag: B[k][n]=K[key=n][d=k].
    floatx4 sacc0 = floatx4{0.f, 0.f, 0.f, 0.f};
    floatx4 sacc1 = floatx4{0.f, 0.f, 0.f, 0.f};
    {
      const unsigned short* krow0 = kbf + (size_t)(kb + lrow) * (NKV * HD) + kv * HD;
      const unsigned short* krow1 = krow0 + (size_t)16 * (NKV * HD);
#pragma unroll
      for (int s = 0; s < 8; s++) {
        bf16x8 b0 = *reinterpret_cast<const bf16x8*>(&krow0[s * 32 + kgrp * 8]);
        sacc0 = mfma16(qa[s], b0, sacc0);
      }
#pragma unroll
      for (int s = 0; s < 8; s++) {
        bf16x8 b1 = *reinterpret_cast<const bf16x8*>(&krow1[s * 32 + kgrp * 8]);
        sacc1 = mfma16(qa[s], b1, sacc1);
      }
    }
    // online softmax; C layout: row = kgrp*4+r, col = lrow
#pragma unroll
    for (int r = 0; r < 4; r++) {
      const int qr = q0 + kgrp * 4 + r;
      float v0 = sacc0[r] * SCALE_F;
      float v1 = sacc1[r] * SCALE_F;
      if (kb + lrow > qr) v0 = -INFINITY;
      if (kb + 16 + lrow > qr) v1 = -INFINITY;
      float mx = fmaxf(v0, v1);
#pragma unroll
      for (int mm = 8; mm >= 1; mm >>= 1) mx = fmaxf(mx, __shfl_xor(mx, mm));
      float mn = fmaxf(m_i[r], mx);
      float alpha = __expf(m_i[r] - mn);  // exp(-inf)=0 first iter
      float p0 = __expf(v0 - mn);
      float p1 = __expf(v1 - mn);
      float rs = p0 + p1;
#pragma unroll
      for (int mm = 8; mm >= 1; mm >>= 1) rs += __shfl_xor(rs, mm);
      l_i[r] = l_i[r] * alpha + rs;
      m_i[r] = mn;
#pragma unroll
      for (int dt = 0; dt < 16; dt++) oacc[dt][r] *= alpha;
      Pl[wave][(kgrp * 4 + r) * 32 + lrow] = f2bf(p0);
      Pl[wave][(kgrp * 4 + r) * 32 + 16 + lrow] = f2bf(p1);
    }
    // P: C-layout -> A-layout via per-wave LDS (wave-internal, lgkmcnt-ordered)
    bf16x8 pa = *reinterpret_cast<const bf16x8*>(&Pl[wave][lrow * 32 + kgrp * 8]);
    // PV: B[k=key][n=dim] = vT[kv*D + dim][key], contiguous over key
    const unsigned short* vbase = vT + (size_t)(kv * HD) * T_LEN + kb + kgrp * 8;
#pragma unroll
    for (int dt = 0; dt < 16; dt++) {
      bf16x8 bv = *reinterpret_cast<const bf16x8*>(&vbase[(size_t)(dt * 16 + lrow) * T_LEN]);
      oacc[dt] = mfma16(pa, bv, oacc[dt]);
    }
  }

  // epilogue: o/l * sigmoid(gate), bf16 store
#pragma unroll
  for (int r = 0; r < 4; r++) {
    const int row = q0 + kgrp * 4 + r;
    const float inv_l = 1.0f / l_i[r];
    const unsigned short* grow = qout + (size_t)row * (NH * 2 * HD) + h * (2 * HD) + HD;
    unsigned short* orow = og + (size_t)row * (NH * HD) + h * HD;
#pragma unroll
    for (int dt = 0; dt < 16; dt++) {
      int dim = dt * 16 + lrow;
      float g = bf2f(grow[dim]);
      float val = oacc[dt][r] * inv_l;
      val *= 1.0f / (1.0f + __expf(-g));
      orow[dim] = f2bf(val);
    }
  }
}

extern "C" void kernel_launch(void* const* d_in, const int* in_sizes, int n_in,
                              void* d_out, int out_size, void* d_ws, size_t ws_size,
                              hipStream_t stream) {
  const int* positions = (const int*)d_in[0];
  const float* hidden = (const float*)d_in[1];
  const float* wq = (const float*)d_in[2];
  const float* wk = (const float*)d_in[3];
  const float* wv = (const float*)d_in[4];
  const float* wo = (const float*)d_in[5];
  const float* qnw = (const float*)d_in[6];
  const float* knw = (const float*)d_in[7];
  float* out = (float*)d_out;

  char* ws = (char*)d_ws;
  size_t off = 0;
  auto alloc = [&](size_t elems) -> unsigned short* {
    unsigned short* p = (unsigned short*)(ws + off);
    off += (elems * 2 + 255) & ~(size_t)255;
    return p;
  };
  unsigned short* hsb = alloc((size_t)T_LEN * HID_DIM);          // 8 MB
  unsigned short* wqb = alloc((size_t)NH * 2 * HD * HID_DIM);    // 33.5 MB
  unsigned short* wkb = alloc((size_t)NKV * HD * HID_DIM);       // 2 MB
  unsigned short* wvb = alloc((size_t)NKV * HD * HID_DIM);       // 2 MB
  unsigned short* wob = alloc((size_t)HID_DIM * NH * HD);        // 16.8 MB
  unsigned short* qout = alloc((size_t)T_LEN * NH * 2 * HD);     // 33.5 MB
  unsigned short* kraw = alloc((size_t)T_LEN * NKV * HD);        // 2 MB
  unsigned short* vraw = alloc((size_t)T_LEN * NKV * HD);        // 2 MB
  unsigned short* qbf = alloc((size_t)T_LEN * NH * HD);          // 16.8 MB
  unsigned short* kbf = alloc((size_t)T_LEN * NKV * HD);         // 2 MB
  unsigned short* vTb = alloc((size_t)NKV * HD * T_LEN);         // 2 MB
  unsigned short* og = alloc((size_t)T_LEN * NH * HD);           // 16.8 MB
  // total ~138 MB of ws

  // bf16 conversions
  cvt_f32_bf16<<<(T_LEN * HID_DIM / 4) / 256, 256, 0, stream>>>(hidden, hsb, T_LEN * HID_DIM / 4);
  cvt_f32_bf16<<<(NH * 2 * HD * HID_DIM / 4) / 256, 256, 0, stream>>>(wq, wqb, NH * 2 * HD * HID_DIM / 4);
  cvt_f32_bf16<<<(NKV * HD * HID_DIM / 4) / 256, 256, 0, stream>>>(wk, wkb, NKV * HD * HID_DIM / 4);
  cvt_f32_bf16<<<(NKV * HD * HID_DIM / 4) / 256, 256, 0, stream>>>(wv, wvb, NKV * HD * HID_DIM / 4);
  cvt_f32_bf16<<<(HID_DIM * NH * HD / 4) / 256, 256, 0, stream>>>(wo, wob, HID_DIM * NH * HD / 4);

  // projections (bf16 out)
  gemm_bf16_bt<<<dim3(8192 / 128, 2048 / 128), 256, 0, stream>>>(hsb, wqb, qout, 2048, 8192, 2048, 1);
  gemm_bf16_bt<<<dim3(512 / 128, 2048 / 128), 256, 0, stream>>>(hsb, wkb, kraw, 2048, 512, 2048, 1);
  gemm_bf16_bt<<<dim3(512 / 128, 2048 / 128), 256, 0, stream>>>(hsb, wvb, vraw, 2048, 512, 2048, 1);

  // q/k rmsnorm + rope; v transpose
  norm_rope<<<dim3(T_LEN, NH), 256, 0, stream>>>(qout, qnw, positions, qbf, NH * 2 * HD, 2 * HD, NH * HD);
  norm_rope<<<dim3(T_LEN, NKV), 256, 0, stream>>>(kraw, knw, positions, kbf, NKV * HD, HD, NKV * HD);
  vtrans<<<(NKV * HD * T_LEN) / 256, 256, 0, stream>>>(vraw, vTb);

  // flash attention + gate
  attn_fwd<<<dim3(T_LEN / 64, NH), 256, 0, stream>>>(qbf, kbf, vTb, qout, og);

  // output projection (fp32 out -> d_out)
  gemm_bf16_bt<<<dim3(2048 / 128, 2048 / 128), 256, 0, stream>>>(og, wob, out, 2048, 2048, 4096, 0);
}

// Round 2
// 702.789 us; speedup vs baseline: 1.3260x; 1.3260x over previous
//
#include <hip/hip_runtime.h>
#include <hip/hip_bf16.h>

#define T_LEN 2048
#define HID_DIM 2048
#define NH 16
#define NKV 2
#define HD 256
#define ROT 64
#define EPS_F 1e-6f
#define SCALE_F 0.0625f   // 256^-0.5
#define THETA_F 10000000.0f

typedef __bf16 bf16x8 __attribute__((ext_vector_type(8)));
typedef float floatx4 __attribute__((ext_vector_type(4)));

__device__ __forceinline__ unsigned short f2bf(float x) {
  unsigned int u = __float_as_uint(x);
  unsigned int rounding = 0x7FFFu + ((u >> 16) & 1u);
  return (unsigned short)((u + rounding) >> 16);
}
__device__ __forceinline__ float bf2f(unsigned short u) {
  return __uint_as_float(((unsigned int)u) << 16);
}
__device__ __forceinline__ floatx4 mfma16(bf16x8 a, bf16x8 b, floatx4 c) {
  return __builtin_amdgcn_mfma_f32_16x16x32_bf16(a, b, c, 0, 0, 0);
}
// async global->LDS, 16B/lane, lands at (wave-uniform lds base) + lane*16
__device__ __forceinline__ void gl_lds16(const unsigned short* g, unsigned short* l) {
  __builtin_amdgcn_global_load_lds(
      (const __attribute__((address_space(1))) unsigned int*)g,
      (__attribute__((address_space(3))) unsigned int*)l, 16, 0, 0);
}

// ---------------- fp32 -> bf16 conversion (vectorized x4) ----------------
__global__ __launch_bounds__(256) void cvt_f32_bf16(
    const float* __restrict__ in, unsigned short* __restrict__ out, int n4) {
  int i = blockIdx.x * 256 + threadIdx.x;
  if (i >= n4) return;
  float4 v = reinterpret_cast<const float4*>(in)[i];
  ushort4 o;
  o.x = f2bf(v.x); o.y = f2bf(v.y); o.z = f2bf(v.z); o.w = f2bf(v.w);
  reinterpret_cast<ushort4*>(out)[i] = o;
}

// ---------------- bf16 GEMM: C[M,N] = A[M,K] * B[N,K]^T ----------------
// 128x128 tile, BK=32, 4 waves (2x2), global_load_lds width-16 staging (m97).
__global__ __launch_bounds__(256) void gemm_bf16_bt(
    const unsigned short* __restrict__ A,
    const unsigned short* __restrict__ B,
    void* __restrict__ Cv, int M, int N, int K, int c_bf16) {
  __shared__ alignas(16) unsigned short As[128 * 32];
  __shared__ alignas(16) unsigned short Bs[128 * 32];
  const int tid = threadIdx.x;
  const int m0 = blockIdx.y * 128;
  const int n0 = blockIdx.x * 128;
  const int lane = tid & 63;
  const int wave = tid >> 6;
  const int wm = (wave >> 1) * 64;
  const int wn = (wave & 1) * 64;
  const int lrow = lane & 15;
  const int kgrp = lane >> 4;

  // staging addresses: wave covers rows [wave*32, wave*32+32) in 2 insts of 16 rows
  const unsigned short* aG = A + (size_t)(m0 + wave * 32 + (lane >> 2)) * K + (lane & 3) * 8;
  const unsigned short* bG = B + (size_t)(n0 + wave * 32 + (lane >> 2)) * K + (lane & 3) * 8;
  unsigned short* aL0 = &As[(wave * 32) * 32];
  unsigned short* aL1 = &As[(wave * 32 + 16) * 32];
  unsigned short* bL0 = &Bs[(wave * 32) * 32];
  unsigned short* bL1 = &Bs[(wave * 32 + 16) * 32];

  floatx4 acc[4][4];
#pragma unroll
  for (int i = 0; i < 4; i++)
#pragma unroll
    for (int j = 0; j < 4; j++) acc[i][j] = floatx4{0.f, 0.f, 0.f, 0.f};

  for (int k0 = 0; k0 < K; k0 += 32) {
    gl_lds16(aG + k0, aL0);
    gl_lds16(aG + (size_t)16 * K + k0, aL1);
    gl_lds16(bG + k0, bL0);
    gl_lds16(bG + (size_t)16 * K + k0, bL1);
    __syncthreads();
    bf16x8 af[4], bfr[4];
#pragma unroll
    for (int i = 0; i < 4; i++)
      af[i] = *reinterpret_cast<const bf16x8*>(&As[(wm + i * 16 + lrow) * 32 + kgrp * 8]);
#pragma unroll
    for (int j = 0; j < 4; j++)
      bfr[j] = *reinterpret_cast<const bf16x8*>(&Bs[(wn + j * 16 + lrow) * 32 + kgrp * 8]);
#pragma unroll
    for (int i = 0; i < 4; i++)
#pragma unroll
      for (int j = 0; j < 4; j++)
        acc[i][j] = mfma16(af[i], bfr[j], acc[i][j]);
    __syncthreads();
  }

  // C/D layout: col = lane&15, row = (lane>>4)*4 + reg  [m89/m91 verified]
  if (c_bf16) {
    unsigned short* C = (unsigned short*)Cv;
#pragma unroll
    for (int i = 0; i < 4; i++) {
      int row = m0 + wm + i * 16 + kgrp * 4;
#pragma unroll
      for (int j = 0; j < 4; j++) {
        int col = n0 + wn + j * 16 + lrow;
#pragma unroll
        for (int r = 0; r < 4; r++)
          C[(size_t)(row + r) * N + col] = f2bf(acc[i][j][r]);
      }
    }
  } else {
    float* C = (float*)Cv;
#pragma unroll
    for (int i = 0; i < 4; i++) {
      int row = m0 + wm + i * 16 + kgrp * 4;
#pragma unroll
      for (int j = 0; j < 4; j++) {
        int col = n0 + wn + j * 16 + lrow;
#pragma unroll
        for (int r = 0; r < 4; r++)
          C[(size_t)(row + r) * N + col] = acc[i][j][r];
      }
    }
  }
}

// ---------------- RMSNorm + partial RoPE (per (t, head), D=256) ----------------
__global__ __launch_bounds__(256) void norm_rope(
    const unsigned short* __restrict__ in, const float* __restrict__ w,
    const int* __restrict__ pos, unsigned short* __restrict__ outb,
    int in_rs, int in_hs, int out_rs) {
  const int t = blockIdx.x, h = blockIdx.y, d = threadIdx.x;
  float x = bf2f(in[(size_t)t * in_rs + h * in_hs + d]);
  float ss = x * x;
#pragma unroll
  for (int m = 32; m >= 1; m >>= 1) ss += __shfl_xor(ss, m);
  __shared__ float wsum[4];
  if ((d & 63) == 0) wsum[d >> 6] = ss;
  __syncthreads();
  float tot = (wsum[0] + wsum[1]) + (wsum[2] + wsum[3]);
  float rms = rsqrtf(tot * (1.0f / 256.0f) + EPS_F);
  float y = x * rms * (1.0f + w[d]);
  float o = y;
  if (d < ROT) {
    float partner = __shfl_xor(y, ROT / 2);
    int i = d & (ROT / 2 - 1);
    float fr = (float)pos[t] * powf(THETA_F, -(float)i / (float)(ROT / 2));
    float c = cosf(fr), s = sinf(fr);
    o = (d < ROT / 2) ? (y * c - partner * s) : (partner * s + y * c);
  }
  outb[(size_t)t * out_rs + h * HD + d] = f2bf(o);
}

// ---------------- V transpose: (T, cols at src_off..+512) -> (512, T) ----------------
__global__ __launch_bounds__(256) void vtrans(
    const unsigned short* __restrict__ vin, unsigned short* __restrict__ vT,
    int src_stride, int src_off) {
  int gid = blockIdx.x * 256 + threadIdx.x;  // gid = c*T + t
  int t = gid & (T_LEN - 1);
  int c = gid >> 11;
  vT[gid] = vin[(size_t)t * src_stride + src_off + c];
}

// ---------------- Flash attention v2: paired tiles, 32 q-rows/wave ----------------
__device__ __forceinline__ void softmax_upd(
    floatx4 (&s)[4], float (&m_i)[4], float (&l_i)[4], floatx4 (&oacc)[16],
    unsigned short* Pbuf, int kb, int q0, int kgrp, int lrow) {
#pragma unroll
  for (int r = 0; r < 4; ++r) {
    const int qr = q0 + kgrp * 4 + r;
    float v0 = (kb + lrow > qr) ? -INFINITY : s[0][r] * SCALE_F;
    float v1 = (kb + 16 + lrow > qr) ? -INFINITY : s[1][r] * SCALE_F;
    float v2 = (kb + 32 + lrow > qr) ? -INFINITY : s[2][r] * SCALE_F;
    float v3 = (kb + 48 + lrow > qr) ? -INFINITY : s[3][r] * SCALE_F;
    float mx = fmaxf(fmaxf(v0, v1), fmaxf(v2, v3));
#pragma unroll
    for (int mm = 8; mm >= 1; mm >>= 1) mx = fmaxf(mx, __shfl_xor(mx, mm));
    float mn = fmaxf(m_i[r], mx);
    float al = __expf(m_i[r] - mn);  // exp(-inf)=0 first iter
    float p0 = __expf(v0 - mn), p1 = __expf(v1 - mn);
    float p2 = __expf(v2 - mn), p3 = __expf(v3 - mn);
    float rs = (p0 + p1) + (p2 + p3);
#pragma unroll
    for (int mm = 8; mm >= 1; mm >>= 1) rs += __shfl_xor(rs, mm);
    l_i[r] = l_i[r] * al + rs;
    m_i[r] = mn;
#pragma unroll
    for (int dt = 0; dt < 16; dt++) oacc[dt][r] *= al;
    const int prow = (kgrp * 4 + r) * 64 + lrow;
    Pbuf[prow] = f2bf(p0);
    Pbuf[prow + 16] = f2bf(p1);
    Pbuf[prow + 32] = f2bf(p2);
    Pbuf[prow + 48] = f2bf(p3);
  }
}

__device__ __forceinline__ void attn_epilogue(
    const floatx4 (&oacc)[16], const float (&l_i)[4],
    const unsigned short* __restrict__ qout, unsigned short* __restrict__ og,
    int q0, int h, int kgrp, int lrow) {
#pragma unroll
  for (int r = 0; r < 4; ++r) {
    const int row = q0 + kgrp * 4 + r;
    const float inv_l = 1.0f / l_i[r];
    const unsigned short* grow = qout + (size_t)row * (NH * 2 * HD) + h * (2 * HD) + HD;
    unsigned short* orow = og + (size_t)row * (NH * HD) + h * HD;
#pragma unroll
    for (int dt = 0; dt < 16; dt++) {
      int dim = dt * 16 + lrow;
      float g = bf2f(grow[dim]);
      float val = oacc[dt][r] * inv_l;
      val *= 1.0f / (1.0f + __expf(-g));
      orow[dim] = f2bf(val);
    }
  }
}

// Grid (16 pairs, 16 heads), block 256 (4 waves). Wave handles 16 rows of tile
// p AND 16 rows of tile 31-p -> uniform 33 key-block units per wave; K/V frags
// shared by both tiles' MFMAs.
__global__ __launch_bounds__(256, 1) void attn_fwd(
    const unsigned short* __restrict__ qbf,   // (T, H*D) post norm+rope
    const unsigned short* __restrict__ kbf,   // (T, KV*D) post norm+rope
    const unsigned short* __restrict__ vT,    // (KV*D, T)
    const unsigned short* __restrict__ qout,  // (T, H*2D), gate at +D
    unsigned short* __restrict__ og)          // (T, H*D)
{
  const int p = blockIdx.x;
  const int h = blockIdx.y;
  const int wv = threadIdx.x >> 6;
  const int lane = threadIdx.x & 63;
  const int lrow = lane & 15;
  const int kgrp = lane >> 4;
  const int kv = h >> 3;  // H/KV = 8
  const int tB = 31 - p;
  const int q0A = p * 64 + wv * 16;
  const int q0B = tB * 64 + wv * 16;
  const int nbA = p + 1;
  const int nbB = tB + 1;

  __shared__ alignas(16) unsigned short P[4][2][16 * 64];

  bf16x8 qaA[8], qaB[8];
  {
    const unsigned short* qrA = qbf + (size_t)(q0A + lrow) * (NH * HD) + h * HD + kgrp * 8;
    const unsigned short* qrB = qbf + (size_t)(q0B + lrow) * (NH * HD) + h * HD + kgrp * 8;
#pragma unroll
    for (int s = 0; s < 8; s++) {
      qaA[s] = *reinterpret_cast<const bf16x8*>(qrA + s * 32);
      qaB[s] = *reinterpret_cast<const bf16x8*>(qrB + s * 32);
    }
  }

  float mA[4], lA[4], mB[4], lB[4];
#pragma unroll
  for (int r = 0; r < 4; r++) { mA[r] = -INFINITY; lA[r] = 0.f; mB[r] = -INFINITY; lB[r] = 0.f; }
  floatx4 oA[16], oB[16];
#pragma unroll
  for (int dt = 0; dt < 16; dt++) { oA[dt] = floatx4{0.f,0.f,0.f,0.f}; oB[dt] = floatx4{0.f,0.f,0.f,0.f}; }

  for (int ib = 0; ib < nbB; ++ib) {
    const int kb = ib * 64;
    const bool doA = ib < nbA;
    const int jmA = (ib == nbA - 1) ? wv : 3;   // last A-block: j>wv fully masked
    const int jmB = (ib == nbB - 1) ? wv : 3;

    floatx4 sA[4], sB[4];
#pragma unroll
    for (int j = 0; j < 4; j++) { sA[j] = floatx4{0.f,0.f,0.f,0.f}; sB[j] = floatx4{0.f,0.f,0.f,0.f}; }

    const unsigned short* kr = kbf + (size_t)(kb + lrow) * (NKV * HD) + kv * HD + kgrp * 8;
#pragma unroll
    for (int j = 0; j < 4; ++j) {
      const bool nA = doA && (j <= jmA);
      const bool nB = (j <= jmB);
      if (!(nA || nB)) continue;
      const unsigned short* krj = kr + (size_t)j * 16 * (NKV * HD);
      bf16x8 kf[8];
#pragma unroll
      for (int s = 0; s < 8; s++) kf[s] = *reinterpret_cast<const bf16x8*>(krj + s * 32);
      if (nA) {
#pragma unroll
        for (int s = 0; s < 8; s++) sA[j] = mfma16(qaA[s], kf[s], sA[j]);
      }
      if (nB) {
#pragma unroll
        for (int s = 0; s < 8; s++) sB[j] = mfma16(qaB[s], kf[s], sB[j]);
      }
    }

    if (doA) softmax_upd(sA, mA, lA, oA, &P[wv][0][0], kb, q0A, kgrp, lrow);
    softmax_upd(sB, mB, lB, oB, &P[wv][1][0], kb, q0B, kgrp, lrow);

    // P: C-layout -> A-layout via per-wave LDS (wave-internal, lgkmcnt-ordered)
    bf16x8 pA0, pA1, pB0, pB1;
    pA0 = *reinterpret_cast<const bf16x8*>(&P[wv][0][lrow * 64 + kgrp * 8]);
    pA1 = *reinterpret_cast<const bf16x8*>(&P[wv][0][lrow * 64 + 32 + kgrp * 8]);
    pB0 = *reinterpret_cast<const bf16x8*>(&P[wv][1][lrow * 64 + kgrp * 8]);
    pB1 = *reinterpret_cast<const bf16x8*>(&P[wv][1][lrow * 64 + 32 + kgrp * 8]);

    const unsigned short* vb = vT + (size_t)(kv * HD + lrow) * T_LEN + kb + kgrp * 8;
#pragma unroll
    for (int dt = 0; dt < 16; ++dt) {
      bf16x8 v0 = *reinterpret_cast<const bf16x8*>(vb + (size_t)dt * 16 * T_LEN);
      bf16x8 v1 = *reinterpret_cast<const bf16x8*>(vb + (size_t)dt * 16 * T_LEN + 32);
      if (doA) {
        oA[dt] = mfma16(pA0, v0, oA[dt]);
        oA[dt] = mfma16(pA1, v1, oA[dt]);
      }
      oB[dt] = mfma16(pB0, v0, oB[dt]);
      oB[dt] = mfma16(pB1, v1, oB[dt]);
    }
  }

  attn_epilogue(oA, lA, qout, og, q0A, h, kgrp, lrow);
  attn_epilogue(oB, lB, qout, og, q0B, h, kgrp, lrow);
}

extern "C" void kernel_launch(void* const* d_in, const int* in_sizes, int n_in,
                              void* d_out, int out_size, void* d_ws, size_t ws_size,
                              hipStream_t stream) {
  const int* positions = (const int*)d_in[0];
  const float* hidden = (const float*)d_in[1];
  const float* wq = (const float*)d_in[2];
  const float* wk = (const float*)d_in[3];
  const float* wv = (const float*)d_in[4];
  const float* wo = (const float*)d_in[5];
  const float* qnw = (const float*)d_in[6];
  const float* knw = (const float*)d_in[7];
  float* out = (float*)d_out;

  char* ws = (char*)d_ws;
  size_t off = 0;
  auto alloc = [&](size_t elems) -> unsigned short* {
    unsigned short* p = (unsigned short*)(ws + off);
    off += (elems * 2 + 255) & ~(size_t)255;
    return p;
  };
  unsigned short* hsb  = alloc((size_t)T_LEN * HID_DIM);
  unsigned short* wqb  = alloc((size_t)NH * 2 * HD * HID_DIM);
  unsigned short* wkvb = alloc((size_t)2 * NKV * HD * HID_DIM);   // wk rows then wv rows
  unsigned short* wob  = alloc((size_t)HID_DIM * NH * HD);
  unsigned short* qout = alloc((size_t)T_LEN * NH * 2 * HD);
  unsigned short* kvraw= alloc((size_t)T_LEN * 2 * NKV * HD);     // cols 0-511 K, 512-1023 V
  unsigned short* qbf  = alloc((size_t)T_LEN * NH * HD);
  unsigned short* kbf  = alloc((size_t)T_LEN * NKV * HD);
  unsigned short* vTb  = alloc((size_t)NKV * HD * T_LEN);
  unsigned short* og   = alloc((size_t)T_LEN * NH * HD);

  // bf16 conversions
  cvt_f32_bf16<<<(T_LEN * HID_DIM / 4) / 256, 256, 0, stream>>>(hidden, hsb, T_LEN * HID_DIM / 4);
  cvt_f32_bf16<<<(NH * 2 * HD * HID_DIM / 4) / 256, 256, 0, stream>>>(wq, wqb, NH * 2 * HD * HID_DIM / 4);
  cvt_f32_bf16<<<(NKV * HD * HID_DIM / 4) / 256, 256, 0, stream>>>(wk, wkvb, NKV * HD * HID_DIM / 4);
  cvt_f32_bf16<<<(NKV * HD * HID_DIM / 4) / 256, 256, 0, stream>>>(wv, wkvb + (size_t)NKV * HD * HID_DIM, NKV * HD * HID_DIM / 4);
  cvt_f32_bf16<<<(HID_DIM * NH * HD / 4) / 256, 256, 0, stream>>>(wo, wob, HID_DIM * NH * HD / 4);

  // projections (bf16 out)
  gemm_bf16_bt<<<dim3(8192 / 128, 2048 / 128), 256, 0, stream>>>(hsb, wqb, qout, 2048, 8192, 2048, 1);
  gemm_bf16_bt<<<dim3(1024 / 128, 2048 / 128), 256, 0, stream>>>(hsb, wkvb, kvraw, 2048, 1024, 2048, 1);

  // q/k rmsnorm + rope; v transpose
  norm_rope<<<dim3(T_LEN, NH), 256, 0, stream>>>(qout, qnw, positions, qbf, NH * 2 * HD, 2 * HD, NH * HD);
  norm_rope<<<dim3(T_LEN, NKV), 256, 0, stream>>>(kvraw, knw, positions, kbf, 2 * NKV * HD, HD, NKV * HD);
  vtrans<<<(NKV * HD * T_LEN) / 256, 256, 0, stream>>>(kvraw, vTb, 2 * NKV * HD, NKV * HD);

  // flash attention + gate
  attn_fwd<<<dim3(16, NH), 256, 0, stream>>>(qbf, kbf, vTb, qout, og);

  // output projection (fp32 out -> d_out)
  gemm_bf16_bt<<<dim3(2048 / 128, 2048 / 128), 256, 0, stream>>>(og, wob, out, 2048, 2048, 4096, 0);
}

// Round 3
// 575.444 us; speedup vs baseline: 1.6194x; 1.2213x over previous
//
#include <hip/hip_runtime.h>
#include <hip/hip_bf16.h>

#define T_LEN 2048
#define HID_DIM 2048
#define NH 16
#define NKV 2
#define HD 256
#define ROT 64
#define EPS_F 1e-6f
#define SCALE_F 0.0625f   // 256^-0.5
#define THETA_F 10000000.0f

typedef __bf16 bf16x8 __attribute__((ext_vector_type(8)));
typedef float floatx4 __attribute__((ext_vector_type(4)));

__device__ __forceinline__ unsigned short f2bf(float x) {
  unsigned int u = __float_as_uint(x);
  unsigned int rounding = 0x7FFFu + ((u >> 16) & 1u);
  return (unsigned short)((u + rounding) >> 16);
}
__device__ __forceinline__ float bf2f(unsigned short u) {
  return __uint_as_float(((unsigned int)u) << 16);
}
__device__ __forceinline__ floatx4 mfma16(bf16x8 a, bf16x8 b, floatx4 c) {
  return __builtin_amdgcn_mfma_f32_16x16x32_bf16(a, b, c, 0, 0, 0);
}
// async global->LDS DMA, 16B/lane: lds dest = wave-uniform base + lane*16
__device__ __forceinline__ void gl_lds16(const unsigned short* g, unsigned short* l) {
  __builtin_amdgcn_global_load_lds(
      (const __attribute__((address_space(1))) unsigned int*)g,
      (__attribute__((address_space(3))) unsigned int*)l, 16, 0, 0);
}

// ---------------- fp32 -> bf16 conversion (vectorized x4) ----------------
__global__ __launch_bounds__(256) void cvt_f32_bf16(
    const float* __restrict__ in, unsigned short* __restrict__ out, int n4) {
  int i = blockIdx.x * 256 + threadIdx.x;
  if (i >= n4) return;
  float4 v = reinterpret_cast<const float4*>(in)[i];
  ushort4 o;
  o.x = f2bf(v.x); o.y = f2bf(v.y); o.z = f2bf(v.z); o.w = f2bf(v.w);
  reinterpret_cast<ushort4*>(out)[i] = o;
}

// ---------------- bf16 GEMM: C[M,N] = A[M,K] * B[N,K]^T ----------------
__global__ __launch_bounds__(256) void gemm_bf16_bt(
    const unsigned short* __restrict__ A,
    const unsigned short* __restrict__ B,
    void* __restrict__ Cv, int M, int N, int K, int c_bf16) {
  __shared__ alignas(16) unsigned short As[128 * 32];
  __shared__ alignas(16) unsigned short Bs[128 * 32];
  const int tid = threadIdx.x;
  const int m0 = blockIdx.y * 128;
  const int n0 = blockIdx.x * 128;
  const int lane = tid & 63;
  const int wave = tid >> 6;
  const int wm = (wave >> 1) * 64;
  const int wn = (wave & 1) * 64;
  const int lrow = lane & 15;
  const int kgrp = lane >> 4;

  const unsigned short* aG = A + (size_t)(m0 + wave * 32 + (lane >> 2)) * K + (lane & 3) * 8;
  const unsigned short* bG = B + (size_t)(n0 + wave * 32 + (lane >> 2)) * K + (lane & 3) * 8;
  unsigned short* aL0 = &As[(wave * 32) * 32];
  unsigned short* aL1 = &As[(wave * 32 + 16) * 32];
  unsigned short* bL0 = &Bs[(wave * 32) * 32];
  unsigned short* bL1 = &Bs[(wave * 32 + 16) * 32];

  floatx4 acc[4][4];
#pragma unroll
  for (int i = 0; i < 4; i++)
#pragma unroll
    for (int j = 0; j < 4; j++) acc[i][j] = floatx4{0.f, 0.f, 0.f, 0.f};

  for (int k0 = 0; k0 < K; k0 += 32) {
    gl_lds16(aG + k0, aL0);
    gl_lds16(aG + (size_t)16 * K + k0, aL1);
    gl_lds16(bG + k0, bL0);
    gl_lds16(bG + (size_t)16 * K + k0, bL1);
    __syncthreads();
    bf16x8 af[4], bfr[4];
#pragma unroll
    for (int i = 0; i < 4; i++)
      af[i] = *reinterpret_cast<const bf16x8*>(&As[(wm + i * 16 + lrow) * 32 + kgrp * 8]);
#pragma unroll
    for (int j = 0; j < 4; j++)
      bfr[j] = *reinterpret_cast<const bf16x8*>(&Bs[(wn + j * 16 + lrow) * 32 + kgrp * 8]);
#pragma unroll
    for (int i = 0; i < 4; i++)
#pragma unroll
      for (int j = 0; j < 4; j++)
        acc[i][j] = mfma16(af[i], bfr[j], acc[i][j]);
    __syncthreads();
  }

  if (c_bf16) {
    unsigned short* C = (unsigned short*)Cv;
#pragma unroll
    for (int i = 0; i < 4; i++) {
      int row = m0 + wm + i * 16 + kgrp * 4;
#pragma unroll
      for (int j = 0; j < 4; j++) {
        int col = n0 + wn + j * 16 + lrow;
#pragma unroll
        for (int r = 0; r < 4; r++)
          C[(size_t)(row + r) * N + col] = f2bf(acc[i][j][r]);
      }
    }
  } else {
    float* C = (float*)Cv;
#pragma unroll
    for (int i = 0; i < 4; i++) {
      int row = m0 + wm + i * 16 + kgrp * 4;
#pragma unroll
      for (int j = 0; j < 4; j++) {
        int col = n0 + wn + j * 16 + lrow;
#pragma unroll
        for (int r = 0; r < 4; r++)
          C[(size_t)(row + r) * N + col] = acc[i][j][r];
      }
    }
  }
}

// ---------------- RMSNorm + partial RoPE (per (t, head), D=256) ----------------
__global__ __launch_bounds__(256) void norm_rope(
    const unsigned short* __restrict__ in, const float* __restrict__ w,
    const int* __restrict__ pos, unsigned short* __restrict__ outb,
    int in_rs, int in_hs, int out_rs) {
  const int t = blockIdx.x, h = blockIdx.y, d = threadIdx.x;
  float x = bf2f(in[(size_t)t * in_rs + h * in_hs + d]);
  float ss = x * x;
#pragma unroll
  for (int m = 32; m >= 1; m >>= 1) ss += __shfl_xor(ss, m);
  __shared__ float wsum[4];
  if ((d & 63) == 0) wsum[d >> 6] = ss;
  __syncthreads();
  float tot = (wsum[0] + wsum[1]) + (wsum[2] + wsum[3]);
  float rms = rsqrtf(tot * (1.0f / 256.0f) + EPS_F);
  float y = x * rms * (1.0f + w[d]);
  float o = y;
  if (d < ROT) {
    float partner = __shfl_xor(y, ROT / 2);
    int i = d & (ROT / 2 - 1);
    float fr = (float)pos[t] * powf(THETA_F, -(float)i / (float)(ROT / 2));
    float c = cosf(fr), s = sinf(fr);
    o = (d < ROT / 2) ? (y * c - partner * s) : (partner * s + y * c);
  }
  outb[(size_t)t * out_rs + h * HD + d] = f2bf(o);
}

// ---------------- V transpose: (T, cols at src_off..+512) -> (512, T) ----------------
__global__ __launch_bounds__(256) void vtrans(
    const unsigned short* __restrict__ vin, unsigned short* __restrict__ vT,
    int src_stride, int src_off) {
  int gid = blockIdx.x * 256 + threadIdx.x;  // gid = c*T + t
  int t = gid & (T_LEN - 1);
  int c = gid >> 11;
  vT[gid] = vin[(size_t)t * src_stride + src_off + c];
}

// ---------------- Flash attention v3 ----------------
// No-max softmax (scores bounded: |q|,|k|<=16 after rmsnorm => |s|<=16, exp in
// fp32 range), K/V staged to LDS via global_load_lds DMA (K single-buffered,
// V double-buffered), XOR-swizzled layouts for conflict-free b128 frag reads.
// Grid (16 pairs, 16 heads), block 256 = 4 waves; wave owns 16 rows of tile p
// and 16 rows of tile 31-p (uniform total work).
__global__ __launch_bounds__(256, 1) void attn_fwd(
    const unsigned short* __restrict__ qbf,   // (T, H*D) post norm+rope
    const unsigned short* __restrict__ kbf,   // (T, KV*D) post norm+rope
    const unsigned short* __restrict__ vT,    // (KV*D, T)
    const unsigned short* __restrict__ qout,  // (T, H*2D), gate at +D
    unsigned short* __restrict__ og)          // (T, H*D)
{
  const int p = blockIdx.x;
  const int h = blockIdx.y;
  const int wv = threadIdx.x >> 6;
  const int lane = threadIdx.x & 63;
  const int lrow = lane & 15;
  const int kgrp = lane >> 4;
  const int kv = h >> 3;  // H/KV = 8
  const int tB = 31 - p;
  const int q0A = p * 64 + wv * 16;
  const int q0B = tB * 64 + wv * 16;
  const int nb = tB * 2 + 2;  // block-uniform number of 32-key blocks

  // K: [key 0..31][dim chunks swizzled: pos = c ^ (key&7)], 16KB
  __shared__ alignas(16) unsigned short Ks[32 * 256];
  // V: [dim 0..255][key chunks swizzled: pos = c ^ (dim&3)], 2x16KB
  __shared__ alignas(16) unsigned short Vs[2][256 * 32];
  // P: per-wave, per-tile 16x32 bf16
  __shared__ alignas(16) unsigned short Ps[4][2][16 * 32];

  // DMA staging: wave wv handles insts [wv*4, wv*4+4) of 16 total per tile.
  auto stage_k = [&](int kb) {
#pragma unroll
    for (int i = 0; i < 4; ++i) {
      const int inst = wv * 4 + i;
      const int key_loc = inst * 2 + (lane >> 5);
      const int c = (lane & 31) ^ (key_loc & 7);
      const unsigned short* g =
          kbf + (size_t)(kb + key_loc) * (NKV * HD) + kv * HD + c * 8;
      gl_lds16(g, &Ks[inst * 512]);
    }
  };
  auto stage_v = [&](int kb, int buf) {
#pragma unroll
    for (int i = 0; i < 4; ++i) {
      const int inst = wv * 4 + i;
      const int dim = inst * 16 + (lane >> 2);
      const int c = (lane & 3) ^ (dim & 3);
      const unsigned short* g =
          vT + (size_t)(kv * HD + dim) * T_LEN + kb + c * 8;
      gl_lds16(g, &Vs[buf][inst * 512]);
    }
  };

  // Q A-fragments (global, once)
  bf16x8 qaA[8], qaB[8];
  {
    const unsigned short* qrA = qbf + (size_t)(q0A + lrow) * (NH * HD) + h * HD + kgrp * 8;
    const unsigned short* qrB = qbf + (size_t)(q0B + lrow) * (NH * HD) + h * HD + kgrp * 8;
#pragma unroll
    for (int s = 0; s < 8; s++) {
      qaA[s] = *reinterpret_cast<const bf16x8*>(qrA + s * 32);
      qaB[s] = *reinterpret_cast<const bf16x8*>(qrB + s * 32);
    }
  }

  float lpA[4] = {0.f, 0.f, 0.f, 0.f}, lpB[4] = {0.f, 0.f, 0.f, 0.f};
  floatx4 oA[16], oB[16];
#pragma unroll
  for (int dt = 0; dt < 16; dt++) { oA[dt] = floatx4{0.f,0.f,0.f,0.f}; oB[dt] = floatx4{0.f,0.f,0.f,0.f}; }

  stage_k(0);
  stage_v(0, 0);

  for (int ib = 0; ib < nb; ++ib) {
    const int kb = ib * 32;
    __syncthreads();  // drains K(ib) + V(ib) DMAs; protects V buffer reuse
    if (ib + 1 < nb) stage_v(kb + 32, (ib + 1) & 1);

    const bool dA = kb <= q0A + 15;
    const bool dB = kb <= q0B + 15;

    // ---- S = Q K^T over 2 j-subtiles of 16 keys ----
    floatx4 sA[2], sB[2];
#pragma unroll
    for (int j = 0; j < 2; j++) { sA[j] = floatx4{0.f,0.f,0.f,0.f}; sB[j] = floatx4{0.f,0.f,0.f,0.f}; }
#pragma unroll
    for (int j = 0; j < 2; ++j) {
      const int ks = kb + j * 16;
      const bool nA = dA && (ks <= q0A + 15);
      const bool nB = dB && (ks <= q0B + 15);
      if (!(nA || nB)) continue;
      bf16x8 kf[8];
#pragma unroll
      for (int s = 0; s < 8; s++)
        kf[s] = *reinterpret_cast<const bf16x8*>(
            &Ks[(j * 16 + lrow) * 256 + (((s * 4 + kgrp) ^ (lrow & 7)) * 8)]);
      if (nA) {
#pragma unroll
        for (int s = 0; s < 8; s++) sA[j] = mfma16(qaA[s], kf[s], sA[j]);
      }
      if (nB) {
#pragma unroll
        for (int s = 0; s < 8; s++) sB[j] = mfma16(qaB[s], kf[s], sB[j]);
      }
    }

    // ---- P = exp(S*scale) with causal mask (no max subtraction) ----
    if (dA) {
#pragma unroll
      for (int r = 0; r < 4; ++r) {
        const int qr = q0A + kgrp * 4 + r;
        float p0 = (kb + lrow <= qr) ? __expf(sA[0][r] * SCALE_F) : 0.f;
        float p1 = (kb + 16 + lrow <= qr) ? __expf(sA[1][r] * SCALE_F) : 0.f;
        lpA[r] += p0 + p1;
        Ps[wv][0][(kgrp * 4 + r) * 32 + lrow] = f2bf(p0);
        Ps[wv][0][(kgrp * 4 + r) * 32 + 16 + lrow] = f2bf(p1);
      }
    }
    if (dB) {
#pragma unroll
      for (int r = 0; r < 4; ++r) {
        const int qr = q0B + kgrp * 4 + r;
        float p0 = (kb + lrow <= qr) ? __expf(sB[0][r] * SCALE_F) : 0.f;
        float p1 = (kb + 16 + lrow <= qr) ? __expf(sB[1][r] * SCALE_F) : 0.f;
        lpB[r] += p0 + p1;
        Ps[wv][1][(kgrp * 4 + r) * 32 + lrow] = f2bf(p0);
        Ps[wv][1][(kgrp * 4 + r) * 32 + 16 + lrow] = f2bf(p1);
      }
    }

    __syncthreads();  // all waves done reading Ks (also drains V(ib+1) DMA)
    if (ib + 1 < nb) stage_k(kb + 32);

    // ---- O += P V ----
    bf16x8 pA, pB;
    if (dA) pA = *reinterpret_cast<const bf16x8*>(&Ps[wv][0][lrow * 32 + kgrp * 8]);
    if (dB) pB = *reinterpret_cast<const bf16x8*>(&Ps[wv][1][lrow * 32 + kgrp * 8]);
    const unsigned short* vsb = &Vs[ib & 1][0];
#pragma unroll
    for (int dt = 0; dt < 16; ++dt) {
      const int d = dt * 16 + lrow;
      bf16x8 bv = *reinterpret_cast<const bf16x8*>(
          &vsb[d * 32 + ((kgrp ^ (lrow & 3)) * 8)]);
      if (dA) oA[dt] = mfma16(pA, bv, oA[dt]);
      if (dB) oB[dt] = mfma16(pB, bv, oB[dt]);
    }
  }

  // ---- reduce l across the 16 row-lanes ----
#pragma unroll
  for (int r = 0; r < 4; ++r) {
#pragma unroll
    for (int m = 8; m >= 1; m >>= 1) {
      lpA[r] += __shfl_xor(lpA[r], m);
      lpB[r] += __shfl_xor(lpB[r], m);
    }
  }

  // ---- epilogue: o/l * sigmoid(gate) ----
#pragma unroll
  for (int t = 0; t < 2; ++t) {
    const int q0 = t ? q0B : q0A;
#pragma unroll
    for (int r = 0; r < 4; ++r) {
      const int row = q0 + kgrp * 4 + r;
      const float inv_l = 1.0f / (t ? lpB[r] : lpA[r]);
      const unsigned short* grow = qout + (size_t)row * (NH * 2 * HD) + h * (2 * HD) + HD;
      unsigned short* orow = og + (size_t)row * (NH * HD) + h * HD;
#pragma unroll
      for (int dt = 0; dt < 16; dt++) {
        int dim = dt * 16 + lrow;
        float g = bf2f(grow[dim]);
        float val = (t ? oB[dt][r] : oA[dt][r]) * inv_l;
        val *= 1.0f / (1.0f + __expf(-g));
        orow[dim] = f2bf(val);
      }
    }
  }
}

extern "C" void kernel_launch(void* const* d_in, const int* in_sizes, int n_in,
                              void* d_out, int out_size, void* d_ws, size_t ws_size,
                              hipStream_t stream) {
  const int* positions = (const int*)d_in[0];
  const float* hidden = (const float*)d_in[1];
  const float* wq = (const float*)d_in[2];
  const float* wk = (const float*)d_in[3];
  const float* wv = (const float*)d_in[4];
  const float* wo = (const float*)d_in[5];
  const float* qnw = (const float*)d_in[6];
  const float* knw = (const float*)d_in[7];
  float* out = (float*)d_out;

  char* ws = (char*)d_ws;
  size_t off = 0;
  auto alloc = [&](size_t elems) -> unsigned short* {
    unsigned short* p = (unsigned short*)(ws + off);
    off += (elems * 2 + 255) & ~(size_t)255;
    return p;
  };
  unsigned short* hsb  = alloc((size_t)T_LEN * HID_DIM);
  unsigned short* wqb  = alloc((size_t)NH * 2 * HD * HID_DIM);
  unsigned short* wkvb = alloc((size_t)2 * NKV * HD * HID_DIM);
  unsigned short* wob  = alloc((size_t)HID_DIM * NH * HD);
  unsigned short* qout = alloc((size_t)T_LEN * NH * 2 * HD);
  unsigned short* kvraw= alloc((size_t)T_LEN * 2 * NKV * HD);
  unsigned short* qbf  = alloc((size_t)T_LEN * NH * HD);
  unsigned short* kbf  = alloc((size_t)T_LEN * NKV * HD);
  unsigned short* vTb  = alloc((size_t)NKV * HD * T_LEN);
  unsigned short* og   = alloc((size_t)T_LEN * NH * HD);

  cvt_f32_bf16<<<(T_LEN * HID_DIM / 4) / 256, 256, 0, stream>>>(hidden, hsb, T_LEN * HID_DIM / 4);
  cvt_f32_bf16<<<(NH * 2 * HD * HID_DIM / 4) / 256, 256, 0, stream>>>(wq, wqb, NH * 2 * HD * HID_DIM / 4);
  cvt_f32_bf16<<<(NKV * HD * HID_DIM / 4) / 256, 256, 0, stream>>>(wk, wkvb, NKV * HD * HID_DIM / 4);
  cvt_f32_bf16<<<(NKV * HD * HID_DIM / 4) / 256, 256, 0, stream>>>(wv, wkvb + (size_t)NKV * HD * HID_DIM, NKV * HD * HID_DIM / 4);
  cvt_f32_bf16<<<(HID_DIM * NH * HD / 4) / 256, 256, 0, stream>>>(wo, wob, HID_DIM * NH * HD / 4);

  gemm_bf16_bt<<<dim3(8192 / 128, 2048 / 128), 256, 0, stream>>>(hsb, wqb, qout, 2048, 8192, 2048, 1);
  gemm_bf16_bt<<<dim3(1024 / 128, 2048 / 128), 256, 0, stream>>>(hsb, wkvb, kvraw, 2048, 1024, 2048, 1);

  norm_rope<<<dim3(T_LEN, NH), 256, 0, stream>>>(qout, qnw, positions, qbf, NH * 2 * HD, 2 * HD, NH * HD);
  norm_rope<<<dim3(T_LEN, NKV), 256, 0, stream>>>(kvraw, knw, positions, kbf, 2 * NKV * HD, HD, NKV * HD);
  vtrans<<<(NKV * HD * T_LEN) / 256, 256, 0, stream>>>(kvraw, vTb, 2 * NKV * HD, NKV * HD);

  attn_fwd<<<dim3(16, NH), 256, 0, stream>>>(qbf, kbf, vTb, qout, og);

  gemm_bf16_bt<<<dim3(2048 / 128, 2048 / 128), 256, 0, stream>>>(og, wob, out, 2048, 2048, 4096, 0);
}

// Round 4
// 547.252 us; speedup vs baseline: 1.7029x; 1.0515x over previous
//
#include <hip/hip_runtime.h>
#include <hip/hip_bf16.h>

#define T_LEN 2048
#define HID_DIM 2048
#define NH 16
#define NKV 2
#define HD 256
#define ROT 64
#define EPS_F 1e-6f
#define SCALE_F 0.0625f   // 256^-0.5
#define THETA_F 10000000.0f

typedef __bf16 bf16x8 __attribute__((ext_vector_type(8)));
typedef float floatx4 __attribute__((ext_vector_type(4)));

__device__ __forceinline__ unsigned short f2bf(float x) {
  unsigned int u = __float_as_uint(x);
  unsigned int rounding = 0x7FFFu + ((u >> 16) & 1u);
  return (unsigned short)((u + rounding) >> 16);
}
__device__ __forceinline__ float bf2f(unsigned short u) {
  return __uint_as_float(((unsigned int)u) << 16);
}
__device__ __forceinline__ floatx4 mfma16(bf16x8 a, bf16x8 b, floatx4 c) {
  return __builtin_amdgcn_mfma_f32_16x16x32_bf16(a, b, c, 0, 0, 0);
}
// async global->LDS DMA, 16B/lane: lds dest = wave-uniform base + lane*16
__device__ __forceinline__ void gl_lds16(const unsigned short* g, unsigned short* l) {
  __builtin_amdgcn_global_load_lds(
      (const __attribute__((address_space(1))) unsigned int*)g,
      (__attribute__((address_space(3))) unsigned int*)l, 16, 0, 0);
}

// ---------------- merged fp32 -> bf16 conversion (5 segments, f4-vectorized) ----------------
__global__ __launch_bounds__(256) void cvt_all(
    const float* __restrict__ hs, const float* __restrict__ wq,
    const float* __restrict__ wk, const float* __restrict__ wv,
    const float* __restrict__ wo, unsigned short* __restrict__ hsb,
    unsigned short* __restrict__ qkvwb, unsigned short* __restrict__ wob) {
  int i = blockIdx.x * 256 + threadIdx.x;  // float4 index, total 7864320
  const float4* s4;
  ushort4* d4;
  int j;
  if (i < 1048576) { s4 = (const float4*)hs; d4 = (ushort4*)hsb; j = i; }
  else if (i < 5242880) { s4 = (const float4*)wq; d4 = (ushort4*)qkvwb; j = i - 1048576; }
  else if (i < 5505024) { s4 = (const float4*)wk; d4 = (ushort4*)qkvwb + 4194304; j = i - 5242880; }
  else if (i < 5767168) { s4 = (const float4*)wv; d4 = (ushort4*)qkvwb + 4456448; j = i - 5505024; }
  else { s4 = (const float4*)wo; d4 = (ushort4*)wob; j = i - 5767168; }
  float4 v = s4[j];
  ushort4 o;
  o.x = f2bf(v.x); o.y = f2bf(v.y); o.z = f2bf(v.z); o.w = f2bf(v.w);
  d4[j] = o;
}

// ---------------- bf16 GEMM: C[M,N] = A[M,K] * B[N,K]^T ----------------
__global__ __launch_bounds__(256) void gemm_bf16_bt(
    const unsigned short* __restrict__ A,
    const unsigned short* __restrict__ B,
    void* __restrict__ Cv, int M, int N, int K, int c_bf16) {
  __shared__ alignas(16) unsigned short As[128 * 32];
  __shared__ alignas(16) unsigned short Bs[128 * 32];
  const int tid = threadIdx.x;
  const int m0 = blockIdx.y * 128;
  const int n0 = blockIdx.x * 128;
  const int lane = tid & 63;
  const int wave = tid >> 6;
  const int wm = (wave >> 1) * 64;
  const int wn = (wave & 1) * 64;
  const int lrow = lane & 15;
  const int kgrp = lane >> 4;

  const unsigned short* aG = A + (size_t)(m0 + wave * 32 + (lane >> 2)) * K + (lane & 3) * 8;
  const unsigned short* bG = B + (size_t)(n0 + wave * 32 + (lane >> 2)) * K + (lane & 3) * 8;
  unsigned short* aL0 = &As[(wave * 32) * 32];
  unsigned short* aL1 = &As[(wave * 32 + 16) * 32];
  unsigned short* bL0 = &Bs[(wave * 32) * 32];
  unsigned short* bL1 = &Bs[(wave * 32 + 16) * 32];

  floatx4 acc[4][4];
#pragma unroll
  for (int i = 0; i < 4; i++)
#pragma unroll
    for (int j = 0; j < 4; j++) acc[i][j] = floatx4{0.f, 0.f, 0.f, 0.f};

  for (int k0 = 0; k0 < K; k0 += 32) {
    gl_lds16(aG + k0, aL0);
    gl_lds16(aG + (size_t)16 * K + k0, aL1);
    gl_lds16(bG + k0, bL0);
    gl_lds16(bG + (size_t)16 * K + k0, bL1);
    __syncthreads();
    bf16x8 af[4], bfr[4];
#pragma unroll
    for (int i = 0; i < 4; i++)
      af[i] = *reinterpret_cast<const bf16x8*>(&As[(wm + i * 16 + lrow) * 32 + kgrp * 8]);
#pragma unroll
    for (int j = 0; j < 4; j++)
      bfr[j] = *reinterpret_cast<const bf16x8*>(&Bs[(wn + j * 16 + lrow) * 32 + kgrp * 8]);
#pragma unroll
    for (int i = 0; i < 4; i++)
#pragma unroll
      for (int j = 0; j < 4; j++)
        acc[i][j] = mfma16(af[i], bfr[j], acc[i][j]);
    __syncthreads();
  }

  if (c_bf16) {
    unsigned short* C = (unsigned short*)Cv;
#pragma unroll
    for (int i = 0; i < 4; i++) {
      int row = m0 + wm + i * 16 + kgrp * 4;
#pragma unroll
      for (int j = 0; j < 4; j++) {
        int col = n0 + wn + j * 16 + lrow;
#pragma unroll
        for (int r = 0; r < 4; r++)
          C[(size_t)(row + r) * N + col] = f2bf(acc[i][j][r]);
      }
    }
  } else {
    float* C = (float*)Cv;
#pragma unroll
    for (int i = 0; i < 4; i++) {
      int row = m0 + wm + i * 16 + kgrp * 4;
#pragma unroll
      for (int j = 0; j < 4; j++) {
        int col = n0 + wn + j * 16 + lrow;
#pragma unroll
        for (int r = 0; r < 4; r++)
          C[(size_t)(row + r) * N + col] = acc[i][j][r];
      }
    }
  }
}

// ---------------- RMSNorm + partial RoPE (per (t, head), D=256) ----------------
__global__ __launch_bounds__(256) void norm_rope(
    const unsigned short* __restrict__ in, const float* __restrict__ w,
    const int* __restrict__ pos, unsigned short* __restrict__ outb,
    int in_rs, int in_hs, int out_rs) {
  const int t = blockIdx.x, h = blockIdx.y, d = threadIdx.x;
  float x = bf2f(in[(size_t)t * in_rs + h * in_hs + d]);
  float ss = x * x;
#pragma unroll
  for (int m = 32; m >= 1; m >>= 1) ss += __shfl_xor(ss, m);
  __shared__ float wsum[4];
  if ((d & 63) == 0) wsum[d >> 6] = ss;
  __syncthreads();
  float tot = (wsum[0] + wsum[1]) + (wsum[2] + wsum[3]);
  float rms = rsqrtf(tot * (1.0f / 256.0f) + EPS_F);
  float y = x * rms * (1.0f + w[d]);
  float o = y;
  if (d < ROT) {
    float partner = __shfl_xor(y, ROT / 2);
    int i = d & (ROT / 2 - 1);
    float fr = (float)pos[t] * powf(THETA_F, -(float)i / (float)(ROT / 2));
    float c = cosf(fr), s = sinf(fr);
    o = (d < ROT / 2) ? (y * c - partner * s) : (partner * s + y * c);
  }
  outb[(size_t)t * out_rs + h * HD + d] = f2bf(o);
}

// ---------------- V transpose: (T, cols src_off..+512) -> (512, T) ----------------
__global__ __launch_bounds__(256) void vtrans(
    const unsigned short* __restrict__ vin, unsigned short* __restrict__ vT,
    int src_stride, int src_off) {
  int gid = blockIdx.x * 256 + threadIdx.x;  // gid = c*T + t
  int t = gid & (T_LEN - 1);
  int c = gid >> 11;
  vT[gid] = vin[(size_t)t * src_stride + src_off + c];
}

// ---------------- Flash attention v4: 8 waves, in-block K-split ----------------
// Block 512 thr (8 waves), grid (16 pairs, 16 heads). Wave (w3=wv&3, half=wv>>2):
// rows w3*16 of tiles (p, 31-p); half 0 takes 32-key chunks kb64+0, half 1
// kb64+32. Uniform 34 chunk-units per block. No-max softmax (|s|<=16 bounded).
// Partial O/l combined through LDS at the epilogue (fp32 exact).
__global__ __launch_bounds__(512, 2) void attn_fwd(
    const unsigned short* __restrict__ qbf,    // (T, H*D) post norm+rope
    const unsigned short* __restrict__ kbf,    // (T, KV*D) post norm+rope
    const unsigned short* __restrict__ vT,     // (KV*D, T)
    const unsigned short* __restrict__ qkvout, // (T, 9216), gate at h*512+256
    unsigned short* __restrict__ og)           // (T, H*D)
{
  const int p = blockIdx.x;
  const int h = blockIdx.y;
  const int wv = threadIdx.x >> 6;
  const int w3 = wv & 3;
  const int half = wv >> 2;
  const int lane = threadIdx.x & 63;
  const int lrow = lane & 15;
  const int kgrp = lane >> 4;
  const int kvh = h >> 3;  // H/KV = 8
  const int tB = 31 - p;
  const int q0A = p * 64 + w3 * 16;
  const int q0B = tB * 64 + w3 * 16;
  const int nb = tB + 1;  // 64-key slabs

  // LDS: Ks 32KB | Vs0 32KB | Vs1 32KB | Ps 20KB  (116KB)
  // Combine overlay: Obuf(64KB) over Ks+Vs0, Lbuf over Ps region.
  __shared__ alignas(16) unsigned char SMEM[118784];
  unsigned short* Ks = (unsigned short*)SMEM;            // [key 0..63][256 d], chunk^=(key&7)
  unsigned short* Vs0 = (unsigned short*)(SMEM + 32768); // [dim 0..255][64 k], chunk^=(dim&7)
  unsigned short* Vs1 = (unsigned short*)(SMEM + 65536);
  unsigned short* Ps = (unsigned short*)(SMEM + 98304) + wv * 1280;  // 2 tiles x 16 x 40
  float* Obuf = (float*)SMEM;
  float* Lbuf = (float*)(SMEM + 98304);

  auto stage_k = [&](int kb64) {
#pragma unroll
    for (int i = 0; i < 4; ++i) {
      const int inst = wv * 4 + i;
      const int key = inst * 2 + (lane >> 5);
      const int c = (lane & 31) ^ (key & 7);
      gl_lds16(kbf + (size_t)(kb64 + key) * (NKV * HD) + kvh * HD + c * 8,
               Ks + inst * 512);
    }
  };
  auto stage_v = [&](int kb64, unsigned short* vbuf) {
#pragma unroll
    for (int i = 0; i < 4; ++i) {
      const int inst = wv * 4 + i;
      const int dim = inst * 8 + (lane >> 3);
      const int c = (lane & 7) ^ (dim & 7);
      gl_lds16(vT + (size_t)(kvh * HD + dim) * T_LEN + kb64 + c * 8,
               vbuf + inst * 512);
    }
  };

  // Q A-fragments (global, once)
  bf16x8 qaA[8], qaB[8];
  {
    const unsigned short* qrA = qbf + (size_t)(q0A + lrow) * (NH * HD) + h * HD + kgrp * 8;
    const unsigned short* qrB = qbf + (size_t)(q0B + lrow) * (NH * HD) + h * HD + kgrp * 8;
#pragma unroll
    for (int s = 0; s < 8; s++) {
      qaA[s] = *reinterpret_cast<const bf16x8*>(qrA + s * 32);
      qaB[s] = *reinterpret_cast<const bf16x8*>(qrB + s * 32);
    }
  }

  float lpA[4] = {0.f, 0.f, 0.f, 0.f}, lpB[4] = {0.f, 0.f, 0.f, 0.f};
  floatx4 oA[16], oB[16];
#pragma unroll
  for (int dt = 0; dt < 16; dt++) { oA[dt] = floatx4{0.f,0.f,0.f,0.f}; oB[dt] = floatx4{0.f,0.f,0.f,0.f}; }

  stage_k(0);
  stage_v(0, Vs0);

  for (int ib = 0; ib < nb; ++ib) {
    const int kb64 = ib * 64;
    const int kb = kb64 + half * 32;  // this wave's 32-key chunk
    unsigned short* Vcur = (ib & 1) ? Vs1 : Vs0;
    __syncthreads();  // drains K(ib)+V(ib) DMA; protects V buffer reuse
    if (ib + 1 < nb) stage_v(kb64 + 64, (ib & 1) ? Vs0 : Vs1);

    const bool dA = kb <= q0A + 15;
    const bool dB = kb <= q0B + 15;

    // ---- S = Q K^T over 2 j-subtiles of 16 keys ----
    floatx4 sA[2], sB[2];
#pragma unroll
    for (int j = 0; j < 2; j++) { sA[j] = floatx4{0.f,0.f,0.f,0.f}; sB[j] = floatx4{0.f,0.f,0.f,0.f}; }
    const unsigned short* kbase = Ks + (half * 32) * 256;
#pragma unroll
    for (int j = 0; j < 2; ++j) {
      const int ks = kb + j * 16;
      const bool nA = dA && (ks <= q0A + 15);
      const bool nB = dB && (ks <= q0B + 15);
      if (!(nA || nB)) continue;
#pragma unroll
      for (int s = 0; s < 8; s++) {
        bf16x8 kf = *reinterpret_cast<const bf16x8*>(
            &kbase[(j * 16 + lrow) * 256 + (((s * 4 + kgrp) ^ (lrow & 7)) * 8)]);
        if (nA) sA[j] = mfma16(qaA[s], kf, sA[j]);
        if (nB) sB[j] = mfma16(qaB[s], kf, sB[j]);
      }
    }

    // ---- P = exp(S*scale), causal mask, no max subtraction ----
    if (dA) {
#pragma unroll
      for (int r = 0; r < 4; ++r) {
        const int qr = q0A + kgrp * 4 + r;
        float p0 = (kb + lrow <= qr) ? __expf(sA[0][r] * SCALE_F) : 0.f;
        float p1 = (kb + 16 + lrow <= qr) ? __expf(sA[1][r] * SCALE_F) : 0.f;
        lpA[r] += p0 + p1;
        Ps[(kgrp * 4 + r) * 40 + lrow] = f2bf(p0);
        Ps[(kgrp * 4 + r) * 40 + 16 + lrow] = f2bf(p1);
      }
    }
    if (dB) {
#pragma unroll
      for (int r = 0; r < 4; ++r) {
        const int qr = q0B + kgrp * 4 + r;
        float p0 = (kb + lrow <= qr) ? __expf(sB[0][r] * SCALE_F) : 0.f;
        float p1 = (kb + 16 + lrow <= qr) ? __expf(sB[1][r] * SCALE_F) : 0.f;
        lpB[r] += p0 + p1;
        Ps[640 + (kgrp * 4 + r) * 40 + lrow] = f2bf(p0);
        Ps[640 + (kgrp * 4 + r) * 40 + 16 + lrow] = f2bf(p1);
      }
    }

    __syncthreads();  // all waves done reading Ks (also drains V(ib+1) DMA)
    if (ib + 1 < nb) stage_k(kb64 + 64);

    // ---- O += P V (C->A via per-wave LDS; V keys chunk = kgrp + 4*half) ----
    bf16x8 pA, pB;
    if (dA) pA = *reinterpret_cast<const bf16x8*>(&Ps[lrow * 40 + kgrp * 8]);
    if (dB) pB = *reinterpret_cast<const bf16x8*>(&Ps[640 + lrow * 40 + kgrp * 8]);
    const int cc = kgrp + 4 * half;
#pragma unroll
    for (int dt = 0; dt < 16; ++dt) {
      const int d = dt * 16 + lrow;
      bf16x8 bv = *reinterpret_cast<const bf16x8*>(&Vcur[d * 64 + ((cc ^ (d & 7)) * 8)]);
      if (dA) oA[dt] = mfma16(pA, bv, oA[dt]);
      if (dB) oB[dt] = mfma16(pB, bv, oB[dt]);
    }
  }

  // ---- in-wave l reduction across the 16 column-lanes ----
#pragma unroll
  for (int r = 0; r < 4; ++r) {
#pragma unroll
    for (int m = 8; m >= 1; m >>= 1) {
      lpA[r] += __shfl_xor(lpA[r], m);
      lpB[r] += __shfl_xor(lpB[r], m);
    }
  }

  // ---- combine halves through LDS (tile A, then tile B) ----
  __syncthreads();
  if (half == 1) {
#pragma unroll
    for (int dt = 0; dt < 16; ++dt)
#pragma unroll
      for (int r = 0; r < 4; ++r)
        Obuf[(w3 * 16 + kgrp * 4 + r) * 256 + dt * 16 + lrow] = oA[dt][r];
    if (lrow == 0) {
#pragma unroll
      for (int r = 0; r < 4; ++r) Lbuf[w3 * 16 + kgrp * 4 + r] = lpA[r];
    }
  }
  __syncthreads();
  if (half == 0) {
#pragma unroll
    for (int dt = 0; dt < 16; ++dt)
#pragma unroll
      for (int r = 0; r < 4; ++r)
        oA[dt][r] += Obuf[(w3 * 16 + kgrp * 4 + r) * 256 + dt * 16 + lrow];
#pragma unroll
    for (int r = 0; r < 4; ++r) lpA[r] += Lbuf[w3 * 16 + kgrp * 4 + r];
  }
  __syncthreads();
  if (half == 1) {
#pragma unroll
    for (int dt = 0; dt < 16; ++dt)
#pragma unroll
      for (int r = 0; r < 4; ++r)
        Obuf[(w3 * 16 + kgrp * 4 + r) * 256 + dt * 16 + lrow] = oB[dt][r];
    if (lrow == 0) {
#pragma unroll
      for (int r = 0; r < 4; ++r) Lbuf[w3 * 16 + kgrp * 4 + r] = lpB[r];
    }
  }
  __syncthreads();
  if (half == 0) {
#pragma unroll
    for (int dt = 0; dt < 16; ++dt)
#pragma unroll
      for (int r = 0; r < 4; ++r)
        oB[dt][r] += Obuf[(w3 * 16 + kgrp * 4 + r) * 256 + dt * 16 + lrow];
#pragma unroll
    for (int r = 0; r < 4; ++r) lpB[r] += Lbuf[w3 * 16 + kgrp * 4 + r];

    // ---- epilogue: o/l * sigmoid(gate) ----
#pragma unroll
    for (int t = 0; t < 2; ++t) {
      const int q0 = t ? q0B : q0A;
#pragma unroll
      for (int r = 0; r < 4; ++r) {
        const int row = q0 + kgrp * 4 + r;
        const float inv_l = 1.0f / (t ? lpB[r] : lpA[r]);
        const unsigned short* grow = qkvout + (size_t)row * 9216 + h * 512 + 256;
        unsigned short* orow = og + (size_t)row * (NH * HD) + h * HD;
#pragma unroll
        for (int dt = 0; dt < 16; dt++) {
          int dim = dt * 16 + lrow;
          float g = bf2f(grow[dim]);
          float val = (t ? oB[dt][r] : oA[dt][r]) * inv_l;
          val *= 1.0f / (1.0f + __expf(-g));
          orow[dim] = f2bf(val);
        }
      }
    }
  }
}

extern "C" void kernel_launch(void* const* d_in, const int* in_sizes, int n_in,
                              void* d_out, int out_size, void* d_ws, size_t ws_size,
                              hipStream_t stream) {
  const int* positions = (const int*)d_in[0];
  const float* hidden = (const float*)d_in[1];
  const float* wq = (const float*)d_in[2];
  const float* wk = (const float*)d_in[3];
  const float* wv = (const float*)d_in[4];
  const float* wo = (const float*)d_in[5];
  const float* qnw = (const float*)d_in[6];
  const float* knw = (const float*)d_in[7];
  float* out = (float*)d_out;

  char* ws = (char*)d_ws;
  size_t off = 0;
  auto alloc = [&](size_t elems) -> unsigned short* {
    unsigned short* p = (unsigned short*)(ws + off);
    off += (elems * 2 + 255) & ~(size_t)255;
    return p;
  };
  unsigned short* hsb    = alloc((size_t)T_LEN * HID_DIM);        // 8.4 MB
  unsigned short* qkvwb  = alloc((size_t)9216 * HID_DIM);         // 37.7 MB (wq|wk|wv rows)
  unsigned short* wob    = alloc((size_t)HID_DIM * NH * HD);      // 16.8 MB
  unsigned short* qkvout = alloc((size_t)T_LEN * 9216);           // 37.7 MB
  unsigned short* qbf    = alloc((size_t)T_LEN * NH * HD);        // 16.8 MB
  unsigned short* kbf    = alloc((size_t)T_LEN * NKV * HD);       // 2.1 MB
  unsigned short* vTb    = alloc((size_t)NKV * HD * T_LEN);       // 2.1 MB
  unsigned short* og     = alloc((size_t)T_LEN * NH * HD);        // 16.8 MB
  // total ~138 MB (same footprint as R3, which fit)

  // conversions (one kernel, 5 segments)
  cvt_all<<<30720, 256, 0, stream>>>(hidden, wq, wk, wv, wo, hsb, qkvwb, wob);

  // fused Q|gate|K|V projection: (2048 x 9216) = hsb @ qkvwb^T
  gemm_bf16_bt<<<dim3(72, 16), 256, 0, stream>>>(hsb, qkvwb, qkvout, 2048, 9216, 2048, 1);

  // q/k rmsnorm + rope; v transpose
  norm_rope<<<dim3(T_LEN, NH), 256, 0, stream>>>(qkvout, qnw, positions, qbf, 9216, 512, NH * HD);
  norm_rope<<<dim3(T_LEN, NKV), 256, 0, stream>>>(qkvout + 8192, knw, positions, kbf, 9216, HD, NKV * HD);
  vtrans<<<(NKV * HD * T_LEN) / 256, 256, 0, stream>>>(qkvout, vTb, 9216, 8704);

  // flash attention + gate
  attn_fwd<<<dim3(16, NH), 512, 0, stream>>>(qbf, kbf, vTb, qkvout, og);

  // output projection (fp32 out -> d_out)
  gemm_bf16_bt<<<dim3(16, 16), 256, 0, stream>>>(og, wob, out, 2048, 2048, 4096, 0);
}